// Round 3
// baseline (558.232 us; speedup 1.0000x reference)
//
#include <hip/hip_runtime.h>

#define TT   2048
#define WIN  512

typedef unsigned short u16;
typedef unsigned long long u64;
typedef __bf16 bf16x8 __attribute__((ext_vector_type(8)));
typedef float  f32x4  __attribute__((ext_vector_type(4)));

__device__ __forceinline__ float bf2f(u16 u){
  unsigned v = ((unsigned)u) << 16;
  return __builtin_bit_cast(float, v);
}
__device__ __forceinline__ u16 f2bf(float f){
  unsigned x = __builtin_bit_cast(unsigned, f);
  unsigned r = x + 0x7fffu + ((x >> 16) & 1u);
  return (u16)(r >> 16);
}
// Load an 8-element bf16 MFMA operand fragment: elements k = base+{0..3} and base+16+{0..3}.
// Both A and B operands use the same k-permutation, so any bijective HW k-order gives exact results.
__device__ __forceinline__ bf16x8 ldfrag(const u16* p){
  union { bf16x8 v; u64 q[2]; } r;
  r.q[0] = *(const u64*)(p);
  r.q[1] = *(const u64*)(p + 16);
  return r.v;
}
__device__ __forceinline__ f32x4 mfma16(bf16x8 a, bf16x8 b, f32x4 c){
  return __builtin_amdgcn_mfma_f32_16x16x32_bf16(a, b, c, 0, 0, 0);
}

// ---------------- dtype detector: are device buffers bf16 or f32? ----------------
// Read first 2048 u16 of x as bf16. True bf16 N(0,1): max|v| ~ 3.5  -> flag=1.
// f32 data read as bf16: low halves have random exponents, virtually certain
// to produce |v| >= 64 (or Inf/NaN) among 1024 samples -> flag=0.
__global__ __launch_bounds__(64) void k_detect(const u16* __restrict__ x, int* __restrict__ flag){
  int lane = threadIdx.x;
  float mx = 0.f;
  for (int i = lane; i < 2048; i += 64){
    float v = fabsf(bf2f(x[i]));
    mx = (v < 64.0f) ? fmaxf(mx, v) : 1e30f;   // NaN/Inf -> 1e30
  }
  #pragma unroll
  for (int d = 32; d; d >>= 1) mx = fmaxf(mx, __shfl_xor(mx, d));
  if (lane == 0) *flag = (mx < 64.0f) ? 1 : 0;
}

// ---------------- input -> bf16 (convert if f32, copy if already bf16) ----------------
__global__ __launch_bounds__(256) void k_cast(const void* __restrict__ src, u16* __restrict__ dst,
                                              int n4, const int* __restrict__ flag){
  int i = blockIdx.x * 256 + threadIdx.x;
  if (i >= n4) return;
  if (*flag){
    *(u64*)(dst + (size_t)i*4) = *(const u64*)((const u16*)src + (size_t)i*4);
  } else {
    float4 v = *(const float4*)((const float*)src + (size_t)i*4);
    u64 pk = (u64)f2bf(v.x) | ((u64)f2bf(v.y)<<16) | ((u64)f2bf(v.z)<<32) | ((u64)f2bf(v.w)<<48);
    *(u64*)(dst + (size_t)i*4) = pk;
  }
}

// ---------------- norm weights -> f32 staging ----------------
__global__ __launch_bounds__(256) void k_wprep(const void* __restrict__ qw, const void* __restrict__ kw,
                                               float* __restrict__ qwf, float* __restrict__ kwf,
                                               const int* __restrict__ flag){
  int i = threadIdx.x;
  int f = *flag;
  qwf[i] = f ? bf2f(((const u16*)qw)[i]) : ((const float*)qw)[i];
  kwf[i] = f ? bf2f(((const u16*)kw)[i]) : ((const float*)kw)[i];
}

// ---------------- rope table: tab[t*256 + 2*i] = cos(t*freq_i), +1 = sin ----------------
__global__ __launch_bounds__(256) void k_tab(float* __restrict__ tab){
  int idx = blockIdx.x * 256 + threadIdx.x;      // 2048*128 total
  int t = idx >> 7, i = idx & 127;
  float fr = powf(10000.0f, (-2.0f / 256.0f) * (float)i);
  float th = (float)t * fr;
  tab[idx*2 + 0] = cosf(th);
  tab[idx*2 + 1] = sinf(th);
}

// ---------------- fused QKV GEMM: [2048,256] x [4608,256]^T -> bf16 raw ----------------
__global__ __launch_bounds__(256) void k_qkv(const u16* __restrict__ x, const u16* __restrict__ wq,
                                             const u16* __restrict__ wkv,
                                             u16* __restrict__ q_raw, u16* __restrict__ kv_raw){
  __shared__ __align__(16) u16 Ax[64*256];
  __shared__ __align__(16) u16 Bw[64*256];
  int m0 = blockIdx.x * 64, n0 = blockIdx.y * 64;
  int tid = threadIdx.x;
  const u16* wsrc = (n0 < 4096) ? (wq + (size_t)n0*256) : (wkv + (size_t)(n0-4096)*256);
  #pragma unroll
  for (int it=0; it<8; ++it){
    int e = it*2048 + tid*8;
    int row = e >> 8, col = e & 255;
    *(uint4*)&Ax[row*256+col] = *(const uint4*)&x[(size_t)(m0+row)*256 + col];
    *(uint4*)&Bw[row*256+col] = *(const uint4*)&wsrc[(size_t)row*256 + col];
  }
  __syncthreads();
  int w = tid >> 6, lane = tid & 63, ml = lane & 15, g = lane >> 4;
  bf16x8 af[8];
  #pragma unroll
  for (int kk=0; kk<8; ++kk) af[kk] = ldfrag(&Ax[(w*16+ml)*256 + kk*32 + 4*g]);
  f32x4 acc[4];
  #pragma unroll
  for (int j=0; j<4; ++j){
    f32x4 s = {0.f,0.f,0.f,0.f};
    #pragma unroll
    for (int kk=0; kk<8; ++kk)
      s = mfma16(af[kk], ldfrag(&Bw[(j*16+ml)*256 + kk*32 + 4*g]), s);
    acc[j] = s;
  }
  #pragma unroll
  for (int j=0; j<4; ++j)
    #pragma unroll
    for (int r=0; r<4; ++r){
      int row = m0 + w*16 + 4*g + r;
      int n   = n0 + j*16 + ml;
      float v = acc[j][r];
      if (n < 4096) q_raw[(size_t)row*4096 + n] = f2bf(v);
      else          kv_raw[(size_t)row*512 + (n - 4096)] = f2bf(v);
    }
}

// ---------------- rope + rmsnorm -> bf16, layout [h][t][d] ----------------
__device__ __forceinline__ void rope_norm_row(const u16* __restrict__ src, const float* __restrict__ tab,
                                              const float* __restrict__ wn, u16* __restrict__ dst, int lane){
  union { u64 q; u16 u[4]; } iv;
  iv.q = *(const u64*)(src + lane*4);
  float v0 = bf2f(iv.u[0]), v1 = bf2f(iv.u[1]), v2 = bf2f(iv.u[2]), v3 = bf2f(iv.u[3]);
  float4 tc = *(const float4*)(tab + lane*4);   // cos0,sin0,cos1,sin1
  float r0 = v0*tc.x - v1*tc.y;
  float r1 = v0*tc.y + v1*tc.x;
  float r2 = v2*tc.z - v3*tc.w;
  float r3 = v2*tc.w + v3*tc.z;
  float ss = r0*r0 + r1*r1 + r2*r2 + r3*r3;
  #pragma unroll
  for (int d=32; d; d>>=1) ss += __shfl_xor(ss, d);
  float sc = rsqrtf(ss * (1.0f/256.0f) + 1.1920929e-07f);
  u64 pk =  (u64)f2bf(r0*sc*wn[lane*4+0])
         | ((u64)f2bf(r1*sc*wn[lane*4+1]) << 16)
         | ((u64)f2bf(r2*sc*wn[lane*4+2]) << 32)
         | ((u64)f2bf(r3*sc*wn[lane*4+3]) << 48);
  *(u64*)(dst + lane*4) = pk;
}

__global__ __launch_bounds__(256) void k_ropenorm(const u16* __restrict__ q_raw, const u16* __restrict__ kv_raw,
                                                  const float* __restrict__ tab, const float* __restrict__ qw,
                                                  const float* __restrict__ kw, u16* __restrict__ qn,
                                                  u16* __restrict__ kn, u16* __restrict__ vn){
  int row  = blockIdx.x * 4 + (threadIdx.x >> 6);
  int lane = threadIdx.x & 63;
  if (row < 16*2048){
    int h = row >> 11, t = row & 2047;
    rope_norm_row(q_raw + (size_t)t*4096 + h*256, tab + (size_t)t*256, qw,
                  qn + ((size_t)h*2048 + t)*256, lane);
  } else if (row < 16*2048 + 2048){
    int t = row - 16*2048;
    rope_norm_row(kv_raw + (size_t)t*512, tab + (size_t)t*256, kw, kn + (size_t)t*256, lane);
  } else {
    int t = row - (16*2048 + 2048);
    const u16* src = kv_raw + (size_t)t*512 + 256;
    *(u64*)(vn + (size_t)t*256 + lane*4) = *(const u64*)(src + lane*4);
  }
}

// ---------------- windowed flash attention (MQA) ----------------
// block = (head, 64-row q tile); 4 waves, each owns 16 q rows. K/V tiles of 64 staged in LDS.
__global__ __launch_bounds__(256) void k_attn(const u16* __restrict__ qn, const u16* __restrict__ kn,
                                              const u16* __restrict__ vn, u16* __restrict__ aout){
  __shared__ __align__(16) u16 Qs[64*256];
  __shared__ __align__(16) u16 Ks[64*256];
  __shared__ __align__(16) u16 Vs[64*256];
  __shared__ __align__(16) u16 Ps[4][16*64];
  int h = blockIdx.x >> 5, qt = blockIdx.x & 31;
  int q0 = qt * 64;
  int tid = threadIdx.x, w = tid>>6, lane = tid&63, ml = lane&15, g = lane>>4;
  const u16* qsrc = qn + ((size_t)h*2048 + q0)*256;
  #pragma unroll
  for (int it=0; it<8; ++it){
    int e = it*2048 + tid*8; int row = e>>8, col = e&255;
    *(uint4*)&Qs[row*256+col] = *(const uint4*)&qsrc[(size_t)row*256+col];
  }
  float m[4], l[4];
  f32x4 o[16];
  f32x4 zero = {0.f,0.f,0.f,0.f};
  #pragma unroll
  for (int r=0;r<4;++r){ m[r] = -1e30f; l[r] = 0.f; }
  #pragma unroll
  for (int f=0;f<16;++f) o[f] = zero;
  int s_lo = q0 - WIN; if (s_lo < 0) s_lo = 0;
  int ntile = (q0 + 64 - s_lo) >> 6;
  int tq = q0 + w*16 + 4*g;   // + r gives this lane's C-rows
  for (int kt=0; kt<ntile; ++kt){
    int s0 = s_lo + kt*64;
    __syncthreads();
    #pragma unroll
    for (int it=0; it<8; ++it){
      int e = it*2048 + tid*8; int row=e>>8, col=e&255;
      *(uint4*)&Ks[row*256+col] = *(const uint4*)&kn[((size_t)(s0+row))*256+col];
      *(uint4*)&Vs[row*256+col] = *(const uint4*)&vn[((size_t)(s0+row))*256+col];
    }
    __syncthreads();
    // S = Q K^T * scale
    bf16x8 af[8];
    #pragma unroll
    for (int kk=0;kk<8;++kk) af[kk] = ldfrag(&Qs[(w*16+ml)*256 + kk*32 + 4*g]);
    f32x4 sa[4];
    #pragma unroll
    for (int j=0;j<4;++j){
      f32x4 s = {0.f,0.f,0.f,0.f};
      #pragma unroll
      for (int kk=0;kk<8;++kk)
        s = mfma16(af[kk], ldfrag(&Ks[(j*16+ml)*256 + kk*32 + 4*g]), s);
      sa[j] = s;
    }
    // mask + scale
    #pragma unroll
    for (int j=0;j<4;++j){
      int s_idx = s0 + j*16 + ml;
      #pragma unroll
      for (int r=0;r<4;++r){
        int t = tq + r;
        float v = sa[j][r] * 0.0625f;
        bool ok = (s_idx <= t) && (t - s_idx <= WIN);
        sa[j][r] = ok ? v : -1e30f;
      }
    }
    // online softmax (row-reduce across the 16 lanes sharing a row)
    float rmax[4];
    #pragma unroll
    for (int r=0;r<4;++r)
      rmax[r] = fmaxf(fmaxf(sa[0][r], sa[1][r]), fmaxf(sa[2][r], sa[3][r]));
    #pragma unroll
    for (int d=1; d<16; d<<=1)
      #pragma unroll
      for (int r=0;r<4;++r) rmax[r] = fmaxf(rmax[r], __shfl_xor(rmax[r], d));
    float corr[4], rsum[4];
    #pragma unroll
    for (int r=0;r<4;++r){
      float mn = fmaxf(m[r], rmax[r]);
      corr[r] = __expf(m[r] - mn);
      m[r] = mn;
      rsum[r] = 0.f;
    }
    #pragma unroll
    for (int j=0;j<4;++j)
      #pragma unroll
      for (int r=0;r<4;++r){
        float p = __expf(sa[j][r] - m[r]);
        sa[j][r] = p;
        rsum[r] += p;
      }
    #pragma unroll
    for (int d=1; d<16; d<<=1)
      #pragma unroll
      for (int r=0;r<4;++r) rsum[r] += __shfl_xor(rsum[r], d);
    #pragma unroll
    for (int r=0;r<4;++r) l[r] = l[r]*corr[r] + rsum[r];
    #pragma unroll
    for (int f=0;f<16;++f)
      #pragma unroll
      for (int r=0;r<4;++r) o[f][r] *= corr[r];
    // P -> LDS (per-wave buffer), then block barrier for cross-lane visibility
    #pragma unroll
    for (int j=0;j<4;++j)
      #pragma unroll
      for (int r=0;r<4;++r)
        Ps[w][(4*g+r)*64 + j*16 + ml] = f2bf(sa[j][r]);
    __syncthreads();
    // O += P V
    #pragma unroll
    for (int kk2=0; kk2<2; ++kk2){
      bf16x8 a = ldfrag(&Ps[w][ml*64 + kk2*32 + 4*g]);
      #pragma unroll
      for (int f=0; f<16; ++f){
        union { bf16x8 v; u16 u[8]; } b;
        int col = f*16 + ml;
        int kb  = kk2*32 + 4*g;
        #pragma unroll
        for (int i=0;i<4;++i){
          b.u[i]   = Vs[(kb+i)*256 + col];
          b.u[4+i] = Vs[(kb+16+i)*256 + col];
        }
        o[f] = mfma16(a, b.v, o[f]);
      }
    }
  }
  #pragma unroll
  for (int f=0; f<16; ++f)
    #pragma unroll
    for (int r=0; r<4; ++r){
      int t = tq + r;
      aout[((size_t)h*2048 + t)*256 + f*16 + ml] = f2bf(o[f][r] / l[r]);
    }
}

// ---------------- out projection: [2048,4096] x [256,4096]^T -> out ----------------
__global__ __launch_bounds__(256) void k_oproj(const u16* __restrict__ aout, const u16* __restrict__ wo,
                                               void* __restrict__ out, const int* __restrict__ flag){
  __shared__ __align__(16) u16 As[64*256];
  __shared__ __align__(16) u16 Bs[64*256];
  int t0 = blockIdx.x * 64, c0 = blockIdx.y * 64;
  int tid = threadIdx.x, w = tid>>6, lane = tid&63, ml = lane&15, g = lane>>4;
  int fl = *flag;
  f32x4 acc[4];
  f32x4 zero = {0.f,0.f,0.f,0.f};
  #pragma unroll
  for (int j=0;j<4;++j) acc[j] = zero;
  for (int kc=0; kc<16; ++kc){
    __syncthreads();
    #pragma unroll
    for (int it=0; it<8; ++it){
      int e = it*2048 + tid*8; int row=e>>8, col=e&255;
      *(uint4*)&As[row*256+col] = *(const uint4*)&aout[((size_t)kc*2048 + t0 + row)*256 + col];
      *(uint4*)&Bs[row*256+col] = *(const uint4*)&wo[((size_t)(c0+row))*4096 + kc*256 + col];
    }
    __syncthreads();
    #pragma unroll
    for (int kk=0;kk<8;++kk){
      bf16x8 a = ldfrag(&As[(w*16+ml)*256 + kk*32 + 4*g]);
      #pragma unroll
      for (int j=0;j<4;++j)
        acc[j] = mfma16(a, ldfrag(&Bs[(j*16+ml)*256 + kk*32 + 4*g]), acc[j]);
    }
  }
  #pragma unroll
  for (int j=0;j<4;++j)
    #pragma unroll
    for (int r=0;r<4;++r){
      int t = t0 + w*16 + 4*g + r;
      int c = c0 + j*16 + ml;
      float v = acc[j][r];
      if (fl) ((u16*)out)[(size_t)t*256 + c] = f2bf(v);
      else    ((float*)out)[(size_t)t*256 + c] = v;
    }
}

extern "C" void kernel_launch(void* const* d_in, const int* in_sizes, int n_in,
                              void* d_out, int out_size, void* d_ws, size_t ws_size,
                              hipStream_t stream) {
  (void)in_sizes; (void)n_in; (void)out_size; (void)ws_size;
  const void* x_r   = d_in[0];
  const void* wq_r  = d_in[1];
  const void* wkv_r = d_in[2];
  const void* wo_r  = d_in[3];
  const void* qw_r  = d_in[4];
  const void* kw_r  = d_in[5];
  char* ws = (char*)d_ws;
  const size_t MB = 1048576;
  // workspace layout (MB offsets), ~43.5 MB; aout aliases dead q_raw
  u16*   xb     = (u16*)  (ws);                 // [0, 1)
  u16*   wqb    = (u16*)  (ws + 1*MB);          // [1, 3)
  u16*   wkvb   = (u16*)  (ws + 3*MB);          // [3, 3.5)
  u16*   wob    = (u16*)  (ws + 3*MB + MB/2);   // [3.5, 5.5)
  float* tab    = (float*)(ws + 5*MB + MB/2);   // [5.5, 7.5)
  u16*   q_raw  = (u16*)  (ws + 7*MB + MB/2);   // [7.5, 23.5)
  u16*   aout   = q_raw;                        // alias: q_raw dead after k_ropenorm
  u16*   kv_raw = (u16*)  (ws + 23*MB + MB/2);  // [23.5, 25.5)
  u16*   qn     = (u16*)  (ws + 25*MB + MB/2);  // [25.5, 41.5)
  u16*   kn     = (u16*)  (ws + 41*MB + MB/2);  // [41.5, 42.5)
  u16*   vn     = (u16*)  (ws + 42*MB + MB/2);  // [42.5, 43.5)
  int*   flag   = (int*)  (ws + 43*MB + MB/2);  // 4 B
  float* qwf    = (float*)(ws + 43*MB + MB/2 + 256);   // 1 KB
  float* kwf    = (float*)(ws + 43*MB + MB/2 + 1280);  // 1 KB

  k_detect<<<dim3(1),   dim3(64),  0, stream>>>((const u16*)x_r, flag);
  k_cast  <<<dim3(512), dim3(256), 0, stream>>>(x_r,   xb,   2048*256/4, flag);
  k_cast  <<<dim3(1024),dim3(256), 0, stream>>>(wq_r,  wqb,  4096*256/4, flag);
  k_cast  <<<dim3(128), dim3(256), 0, stream>>>(wkv_r, wkvb, 512*256/4,  flag);
  k_cast  <<<dim3(1024),dim3(256), 0, stream>>>(wo_r,  wob,  256*4096/4, flag);
  k_wprep <<<dim3(1),   dim3(256), 0, stream>>>(qw_r, kw_r, qwf, kwf, flag);
  k_tab   <<<dim3(1024),dim3(256), 0, stream>>>(tab);
  k_qkv     <<<dim3(32, 72),  dim3(256), 0, stream>>>(xb, wqb, wkvb, q_raw, kv_raw);
  k_ropenorm<<<dim3(9216),    dim3(256), 0, stream>>>(q_raw, kv_raw, tab, qwf, kwf, qn, kn, vn);
  k_attn    <<<dim3(512),     dim3(256), 0, stream>>>(qn, kn, vn, aout);
  k_oproj   <<<dim3(32, 4),   dim3(256), 0, stream>>>(aout, wob, d_out, flag);
}

// Round 4
// 173.049 us; speedup vs baseline: 3.2259x; 3.2259x over previous
//
#include <hip/hip_runtime.h>

#define TT   2048
#define WIN  512

typedef unsigned short u16;
typedef unsigned long long u64;
typedef __bf16 bf16x8 __attribute__((ext_vector_type(8)));
typedef float  f32x4  __attribute__((ext_vector_type(4)));

__device__ __forceinline__ float bf2f(u16 u){
  unsigned v = ((unsigned)u) << 16;
  return __builtin_bit_cast(float, v);
}
__device__ __forceinline__ u16 f2bf(float f){
  unsigned x = __builtin_bit_cast(unsigned, f);
  unsigned r = x + 0x7fffu + ((x >> 16) & 1u);
  return (u16)(r >> 16);
}
__device__ __forceinline__ f32x4 mfma16(bf16x8 a, bf16x8 b, f32x4 c){
  return __builtin_amdgcn_mfma_f32_16x16x32_bf16(a, b, c, 0, 0, 0);
}
// swizzled LDS b128 fragment read: elements (kk*32 + 8g .. +7) of `row`
__device__ __forceinline__ bf16x8 ld512(const u16* buf, int row, int byte){
  return *(const bf16x8*)((const char*)buf + row*512 + (byte ^ ((row&7)<<4)));
}
__device__ __forceinline__ bf16x8 ld128(const u16* buf, int row, int byte){
  return *(const bf16x8*)((const char*)buf + row*128 + (byte ^ ((row&7)<<4)));
}

// ---------------- dtype detector (validated R3) ----------------
__global__ __launch_bounds__(64) void k_detect(const u16* __restrict__ x, int* __restrict__ flag){
  int lane = threadIdx.x;
  float mx = 0.f;
  for (int i = lane; i < 2048; i += 64){
    float v = fabsf(bf2f(x[i]));
    mx = (v < 64.0f) ? fmaxf(mx, v) : 1e30f;
  }
  #pragma unroll
  for (int d = 32; d; d >>= 1) mx = fmaxf(mx, __shfl_xor(mx, d));
  if (lane == 0) *flag = (mx < 64.0f) ? 1 : 0;
}

__global__ __launch_bounds__(256) void k_cast(const void* __restrict__ src, u16* __restrict__ dst,
                                              int n4, const int* __restrict__ flag){
  int i = blockIdx.x * 256 + threadIdx.x;
  if (i >= n4) return;
  if (*flag){
    *(u64*)(dst + (size_t)i*4) = *(const u64*)((const u16*)src + (size_t)i*4);
  } else {
    float4 v = *(const float4*)((const float*)src + (size_t)i*4);
    u64 pk = (u64)f2bf(v.x) | ((u64)f2bf(v.y)<<16) | ((u64)f2bf(v.z)<<32) | ((u64)f2bf(v.w)<<48);
    *(u64*)(dst + (size_t)i*4) = pk;
  }
}

__global__ __launch_bounds__(256) void k_wprep(const void* __restrict__ qw, const void* __restrict__ kw,
                                               float* __restrict__ qwf, float* __restrict__ kwf,
                                               const int* __restrict__ flag){
  int i = threadIdx.x;
  int f = *flag;
  qwf[i] = f ? bf2f(((const u16*)qw)[i]) : ((const float*)qw)[i];
  kwf[i] = f ? bf2f(((const u16*)kw)[i]) : ((const float*)kw)[i];
}

// ---------------- rope table ----------------
__global__ __launch_bounds__(256) void k_tab(float* __restrict__ tab){
  int idx = blockIdx.x * 256 + threadIdx.x;
  int t = idx >> 7, i = idx & 127;
  float fr = exp2f((float)i * (-13.287712379549449f / 128.0f));  // 10000^(-2i/256)
  float th = (float)t * fr;
  tab[idx*2 + 0] = cosf(th);
  tab[idx*2 + 1] = sinf(th);
}

// ---------------- fused QKV GEMM ----------------
__global__ __launch_bounds__(256) void k_qkv(const u16* __restrict__ x, const u16* __restrict__ wq,
                                             const u16* __restrict__ wkv,
                                             u16* __restrict__ q_raw, u16* __restrict__ kv_raw){
  __shared__ __align__(16) u16 Ax[64*256];
  __shared__ __align__(16) u16 Bw[64*256];
  int m0 = blockIdx.x * 64, n0 = blockIdx.y * 64;
  int tid = threadIdx.x;
  const u16* wsrc = (n0 < 4096) ? (wq + (size_t)n0*256) : (wkv + (size_t)(n0-4096)*256);
  int sr = tid >> 5, sk = tid & 31;
  #pragma unroll
  for (int u=0;u<8;++u){
    int r = sr + u*8;
    uint4 a = *(const uint4*)((const char*)(x    + (size_t)(m0+r)*256) + sk*16);
    uint4 b = *(const uint4*)((const char*)(wsrc + (size_t)r*256)      + sk*16);
    *(uint4*)((char*)&Ax[0] + r*512 + ((sk*16) ^ ((r&7)<<4))) = a;
    *(uint4*)((char*)&Bw[0] + r*512 + ((sk*16) ^ ((r&7)<<4))) = b;
  }
  __syncthreads();
  int w = tid>>6, lane = tid&63, ml = lane&15, g = lane>>4;
  int mh = w & 1, nh = w >> 1;
  f32x4 acc[2][2];
  #pragma unroll
  for (int mr=0;mr<2;++mr)
    #pragma unroll
    for (int j=0;j<2;++j) acc[mr][j] = f32x4{0.f,0.f,0.f,0.f};
  #pragma unroll
  for (int kk=0; kk<8; ++kk){
    bf16x8 af[2], bf[2];
    #pragma unroll
    for (int mr=0;mr<2;++mr) af[mr] = ld512(Ax, mh*32 + mr*16 + ml, kk*64 + g*16);
    #pragma unroll
    for (int j=0;j<2;++j)    bf[j]  = ld512(Bw, nh*32 + j*16 + ml,  kk*64 + g*16);
    #pragma unroll
    for (int mr=0;mr<2;++mr)
      #pragma unroll
      for (int j=0;j<2;++j) acc[mr][j] = mfma16(af[mr], bf[j], acc[mr][j]);
  }
  #pragma unroll
  for (int mr=0;mr<2;++mr)
    #pragma unroll
    for (int j=0;j<2;++j)
      #pragma unroll
      for (int r=0;r<4;++r){
        int row = m0 + mh*32 + mr*16 + 4*g + r;
        int n   = n0 + nh*32 + j*16 + ml;
        float v = acc[mr][j][r];
        if (n < 4096) q_raw[(size_t)row*4096 + n] = f2bf(v);
        else          kv_raw[(size_t)row*512 + (n - 4096)] = f2bf(v);
      }
}

// ---------------- rope + rmsnorm -> bf16 ----------------
__device__ __forceinline__ void rope_norm_row(const u16* __restrict__ src, const float* __restrict__ tab,
                                              const float* __restrict__ wn, u16* __restrict__ dst, int lane){
  union { u64 q; u16 u[4]; } iv;
  iv.q = *(const u64*)(src + lane*4);
  float v0 = bf2f(iv.u[0]), v1 = bf2f(iv.u[1]), v2 = bf2f(iv.u[2]), v3 = bf2f(iv.u[3]);
  float4 tc = *(const float4*)(tab + lane*4);
  float r0 = v0*tc.x - v1*tc.y;
  float r1 = v0*tc.y + v1*tc.x;
  float r2 = v2*tc.z - v3*tc.w;
  float r3 = v2*tc.w + v3*tc.z;
  float ss = r0*r0 + r1*r1 + r2*r2 + r3*r3;
  #pragma unroll
  for (int d=32; d; d>>=1) ss += __shfl_xor(ss, d);
  float sc = rsqrtf(ss * (1.0f/256.0f) + 1.1920929e-07f);
  u64 pk =  (u64)f2bf(r0*sc*wn[lane*4+0])
         | ((u64)f2bf(r1*sc*wn[lane*4+1]) << 16)
         | ((u64)f2bf(r2*sc*wn[lane*4+2]) << 32)
         | ((u64)f2bf(r3*sc*wn[lane*4+3]) << 48);
  *(u64*)(dst + lane*4) = pk;
}

__global__ __launch_bounds__(256) void k_ropenorm(const u16* __restrict__ q_raw, const u16* __restrict__ kv_raw,
                                                  const float* __restrict__ tab, const float* __restrict__ qw,
                                                  const float* __restrict__ kw, u16* __restrict__ qn,
                                                  u16* __restrict__ kn){
  int row  = blockIdx.x * 4 + (threadIdx.x >> 6);
  int lane = threadIdx.x & 63;
  if (row < 16*2048){
    int h = row >> 11, t = row & 2047;
    rope_norm_row(q_raw + (size_t)t*4096 + h*256, tab + (size_t)t*256, qw,
                  qn + ((size_t)h*2048 + t)*256, lane);
  } else {
    int t = row - 16*2048;
    rope_norm_row(kv_raw + (size_t)t*512, tab + (size_t)t*256, kw, kn + (size_t)t*256, lane);
  }
}

// ---------------- V transpose: vt[d][t] = v[t][d] ----------------
__global__ __launch_bounds__(256) void k_vtrans(const u16* __restrict__ kv_raw, u16* __restrict__ vt){
  __shared__ u16 Ts[64][72];
  int t0 = blockIdx.x*64, d0 = blockIdx.y*64;
  int tid = threadIdx.x;
  int rr = tid >> 3, c8 = (tid & 7) * 8;
  #pragma unroll
  for (int u=0;u<2;++u){
    int r = rr + u*32;
    uint4 v = *(const uint4*)(kv_raw + (size_t)(t0+r)*512 + 256 + d0 + c8);
    #pragma unroll
    for (int i=0;i<8;++i) Ts[r][c8+i] = ((const u16*)&v)[i];
  }
  __syncthreads();
  #pragma unroll
  for (int u=0;u<2;++u){
    int d = rr + u*32;
    u16 tmp[8];
    #pragma unroll
    for (int i=0;i<8;++i) tmp[i] = Ts[c8+i][d];
    *(uint4*)(vt + (size_t)(d0+d)*2048 + t0 + c8) = *(uint4*)tmp;
  }
}

// ---------------- windowed flash attention (MQA), swapped operands ----------------
// grid 256 = 8 head-pairs x 32 q-tiles(64). 4 waves: wave = (head hp*2+(w>>1), rows mh*32..+31)
__global__ __launch_bounds__(256) void k_attn(const u16* __restrict__ qn, const u16* __restrict__ kn,
                                              const u16* __restrict__ vt, u16* __restrict__ aout){
  __shared__ __align__(16) u16 Ks[64*256];    // K tile (also Q staging), rows 512B swizzled
  __shared__ __align__(16) u16 Vs[256*64];    // V^T tile, rows 128B swizzled
  __shared__ __align__(16) u16 Ps[4][32*64];  // per-wave P [q][k], rows 128B swizzled
  int hp = blockIdx.x >> 5, qt = blockIdx.x & 31;
  int q0 = qt * 64;
  int tid = threadIdx.x, w = tid >> 6, lane = tid & 63, ml = lane & 15, g = lane >> 4;
  int mh = w & 1;
  int hw = hp*2 + (w >> 1);
  int s_lo = q0 - WIN; if (s_lo < 0) s_lo = 0;
  int ntile = (q0 + 64 - s_lo) >> 6;
  int sr = tid >> 5, sk = tid & 31;       // K/Q staging: rows 8u+sr, 32 slots
  int vd = tid >> 3, vs = tid & 7;        // V staging: rows 32u+vd, 8 slots

  // prefetch tile 0 K/V into regs
  uint4 kreg[8], vreg[8];
  #pragma unroll
  for (int u=0;u<8;++u){
    int r = sr + u*8;
    kreg[u] = *(const uint4*)((const char*)(kn + (size_t)(s_lo + r)*256) + sk*16);
    int d = vd + u*32;
    vreg[u] = *(const uint4*)((const char*)(vt + (size_t)d*2048 + s_lo) + vs*16);
  }
  // stage Q (head A then B) through Ks, pick up fragments in regs
  bf16x8 qf[2][8];
  #pragma unroll
  for (int hh=0; hh<2; ++hh){
    const u16* qsrc = qn + ((size_t)(hp*2 + hh)*2048 + q0)*256;
    uint4 qtmp[8];
    #pragma unroll
    for (int u=0;u<8;++u) qtmp[u] = *(const uint4*)((const char*)(qsrc + (size_t)(sr + u*8)*256) + sk*16);
    __syncthreads();
    #pragma unroll
    for (int u=0;u<8;++u){
      int r = sr + u*8;
      *(uint4*)((char*)&Ks[0] + r*512 + ((sk*16) ^ ((r&7)<<4))) = qtmp[u];
    }
    __syncthreads();
    if ((w>>1) == hh){
      #pragma unroll
      for (int nr=0; nr<2; ++nr)
        #pragma unroll
        for (int kk=0; kk<8; ++kk)
          qf[nr][kk] = ld512(Ks, mh*32 + nr*16 + ml, kk*64 + g*16);
    }
  }

  float mx[2] = {-1e30f, -1e30f}, ls[2] = {0.f, 0.f};
  f32x4 o[2][16];
  #pragma unroll
  for (int nr=0;nr<2;++nr)
    #pragma unroll
    for (int f=0; f<16; ++f) o[nr][f] = f32x4{0.f,0.f,0.f,0.f};

  for (int kt=0; kt<ntile; ++kt){
    int s0 = s_lo + kt*64;
    __syncthreads();                       // previous tile's LDS reads done
    #pragma unroll
    for (int u=0;u<8;++u){
      int r = sr + u*8;
      *(uint4*)((char*)&Ks[0] + r*512 + ((sk*16) ^ ((r&7)<<4))) = kreg[u];
      int d = vd + u*32;
      *(uint4*)((char*)&Vs[0] + d*128 + ((vs*16) ^ ((d&7)<<4))) = vreg[u];
    }
    __syncthreads();
    if (kt+1 < ntile){                     // T14: issue next-tile loads before compute
      int s1 = s0 + 64;
      #pragma unroll
      for (int u=0;u<8;++u){
        int r = sr + u*8;
        kreg[u] = *(const uint4*)((const char*)(kn + (size_t)(s1 + r)*256) + sk*16);
        int d = vd + u*32;
        vreg[u] = *(const uint4*)((const char*)(vt + (size_t)d*2048 + s1) + vs*16);
      }
    }
    // S^T = K @ Q: C col = q (ml), row = key (4g+r); j = key tile, nr = q tile
    f32x4 s[2][4];
    #pragma unroll
    for (int nr=0;nr<2;++nr)
      #pragma unroll
      for (int j=0;j<4;++j) s[nr][j] = f32x4{0.f,0.f,0.f,0.f};
    #pragma unroll
    for (int kk=0; kk<8; ++kk)
      #pragma unroll
      for (int j=0;j<4;++j){
        bf16x8 kf = ld512(Ks, j*16 + ml, kk*64 + g*16);
        s[0][j] = mfma16(kf, qf[0][kk], s[0][j]);
        s[1][j] = mfma16(kf, qf[1][kk], s[1][j]);
      }
    // mask + scale + row max (per-lane q = nr*16+ml; reduce over g via xor 16,32)
    float pm[2];
    #pragma unroll
    for (int nr=0;nr<2;++nr){
      int tq = q0 + mh*32 + nr*16 + ml;
      float best = -1e30f;
      #pragma unroll
      for (int j=0;j<4;++j)
        #pragma unroll
        for (int r=0;r<4;++r){
          int key = s0 + j*16 + 4*g + r;
          float v = s[nr][j][r] * 0.0625f;
          bool ok = (key <= tq) && (tq - key <= WIN);
          v = ok ? v : -1e30f;
          s[nr][j][r] = v;
          best = fmaxf(best, v);
        }
      best = fmaxf(best, __shfl_xor(best, 16));
      best = fmaxf(best, __shfl_xor(best, 32));
      pm[nr] = best;
    }
    // T13 defer-max: only rescale when any row grew past mx+8
    bool need = (pm[0] > mx[0] + 8.f) || (pm[1] > mx[1] + 8.f);
    if (__ballot(need)){
      #pragma unroll
      for (int nr=0;nr<2;++nr){
        float mn = fmaxf(mx[nr], pm[nr]);
        float corr = __expf(mx[nr] - mn);
        mx[nr] = mn; ls[nr] *= corr;
        #pragma unroll
        for (int f=0; f<16; ++f) o[nr][f] *= corr;
      }
    }
    // P = exp(S - mx), write to Ps[q][k] (swizzled), accumulate l
    #pragma unroll
    for (int nr=0;nr<2;++nr){
      int rowp = nr*16 + ml;
      float rs = 0.f;
      #pragma unroll
      for (int j=0;j<4;++j)
        #pragma unroll
        for (int r=0;r<4;++r){
          float p = __expf(s[nr][j][r] - mx[nr]);
          rs += p;
          *(u16*)((char*)&Ps[w][0] + rowp*128 + ((2*(j*16 + 4*g + r)) ^ ((rowp&7)<<4))) = f2bf(p);
        }
      rs += __shfl_xor(rs, 16);
      rs += __shfl_xor(rs, 32);
      ls[nr] += rs;
    }
    // O^T += V^T @ P : A = V^T frags, B = P frags
    #pragma unroll
    for (int kk2=0; kk2<2; ++kk2){
      bf16x8 pb[2];
      #pragma unroll
      for (int nr=0;nr<2;++nr) pb[nr] = ld128(&Ps[w][0], nr*16 + ml, kk2*64 + g*16);
      #pragma unroll
      for (int f=0; f<16; ++f){
        bf16x8 vf = ld128(Vs, f*16 + ml, kk2*64 + g*16);
        o[0][f] = mfma16(vf, pb[0], o[0][f]);
        o[1][f] = mfma16(vf, pb[1], o[1][f]);
      }
    }
  }
  // epilogue: O^T element (d=f*16+4g+r, q=nr*16+ml) -> aout[h][t][d], 4 d's pack to u64
  #pragma unroll
  for (int nr=0;nr<2;++nr){
    float inv = 1.0f / ls[nr];
    int tq = q0 + mh*32 + nr*16 + ml;
    u16* dst = aout + ((size_t)hw*2048 + tq)*256;
    #pragma unroll
    for (int f=0; f<16; ++f){
      f32x4 v = o[nr][f];
      u64 pk = (u64)f2bf(v[0]*inv) | ((u64)f2bf(v[1]*inv)<<16)
             | ((u64)f2bf(v[2]*inv)<<32) | ((u64)f2bf(v[3]*inv)<<48);
      *(u64*)(dst + f*16 + 4*g) = pk;
    }
  }
}

// ---------------- out projection, split-K x4 -> f32 partials ----------------
__global__ __launch_bounds__(256) void k_oproj(const u16* __restrict__ aout, const u16* __restrict__ wo,
                                               float* __restrict__ pout){
  __shared__ __align__(16) u16 As[64*256];
  __shared__ __align__(16) u16 Bs[64*256];
  int t0 = blockIdx.x * 64, c0 = blockIdx.y * 64, ksp = blockIdx.z;
  int tid = threadIdx.x, w = tid>>6, lane = tid&63, ml = lane&15, g = lane>>4;
  int mh = w & 1, nh = w >> 1;
  int sr = tid >> 5, sk = tid & 31;
  f32x4 acc[2][2];
  #pragma unroll
  for (int mr=0;mr<2;++mr)
    #pragma unroll
    for (int j=0;j<2;++j) acc[mr][j] = f32x4{0.f,0.f,0.f,0.f};
  for (int kc = ksp*4; kc < ksp*4 + 4; ++kc){
    __syncthreads();
    #pragma unroll
    for (int u=0;u<8;++u){
      int r = sr + u*8;
      uint4 a = *(const uint4*)((const char*)(aout + ((size_t)kc*2048 + t0 + r)*256) + sk*16);
      uint4 b = *(const uint4*)((const char*)(wo + (size_t)(c0+r)*4096 + kc*256) + sk*16);
      *(uint4*)((char*)&As[0] + r*512 + ((sk*16) ^ ((r&7)<<4))) = a;
      *(uint4*)((char*)&Bs[0] + r*512 + ((sk*16) ^ ((r&7)<<4))) = b;
    }
    __syncthreads();
    #pragma unroll
    for (int kk=0; kk<8; ++kk){
      bf16x8 af[2], bf[2];
      #pragma unroll
      for (int mr=0;mr<2;++mr) af[mr] = ld512(As, mh*32 + mr*16 + ml, kk*64 + g*16);
      #pragma unroll
      for (int j=0;j<2;++j)    bf[j]  = ld512(Bs, nh*32 + j*16 + ml,  kk*64 + g*16);
      #pragma unroll
      for (int mr=0;mr<2;++mr)
        #pragma unroll
        for (int j=0;j<2;++j) acc[mr][j] = mfma16(af[mr], bf[j], acc[mr][j]);
    }
  }
  #pragma unroll
  for (int mr=0;mr<2;++mr)
    #pragma unroll
    for (int j=0;j<2;++j)
      #pragma unroll
      for (int r=0;r<4;++r){
        int t = t0 + mh*32 + mr*16 + 4*g + r;
        int c = c0 + nh*32 + j*16 + ml;
        pout[((size_t)ksp*2048 + t)*256 + c] = acc[mr][j][r];
      }
}

__global__ __launch_bounds__(256) void k_red(const float* __restrict__ pout, void* __restrict__ out,
                                             const int* __restrict__ flag){
  int i = blockIdx.x * 256 + threadIdx.x;
  float v = pout[i] + pout[i + 2048*256] + pout[i + 2*2048*256] + pout[i + 3*2048*256];
  if (*flag) ((u16*)out)[i] = f2bf(v);
  else       ((float*)out)[i] = v;
}

extern "C" void kernel_launch(void* const* d_in, const int* in_sizes, int n_in,
                              void* d_out, int out_size, void* d_ws, size_t ws_size,
                              hipStream_t stream) {
  (void)in_sizes; (void)n_in; (void)out_size; (void)ws_size;
  const void* x_r   = d_in[0];
  const void* wq_r  = d_in[1];
  const void* wkv_r = d_in[2];
  const void* wo_r  = d_in[3];
  const void* qw_r  = d_in[4];
  const void* kw_r  = d_in[5];
  char* ws = (char*)d_ws;
  const size_t MB = 1048576;
  u16*   xb     = (u16*)  (ws);                 // [0, 1)
  u16*   wqb    = (u16*)  (ws + 1*MB);          // [1, 3)
  u16*   wkvb   = (u16*)  (ws + 3*MB);          // [3, 3.5)
  u16*   wob    = (u16*)  (ws + 3*MB + MB/2);   // [3.5, 5.5)
  float* tab    = (float*)(ws + 5*MB + MB/2);   // [5.5, 7.5)
  u16*   q_raw  = (u16*)  (ws + 7*MB + MB/2);   // [7.5, 23.5)
  u16*   aout   = q_raw;                        // alias: q_raw dead after k_ropenorm
  u16*   kv_raw = (u16*)  (ws + 23*MB + MB/2);  // [23.5, 25.5)
  u16*   qn     = (u16*)  (ws + 25*MB + MB/2);  // [25.5, 41.5)
  float* pout   = (float*)qn;                   // alias: qn dead after k_attn (8 MB)
  u16*   kn     = (u16*)  (ws + 41*MB + MB/2);  // [41.5, 42.5)
  u16*   vt     = (u16*)  (ws + 42*MB + MB/2);  // [42.5, 43.5)
  int*   flag   = (int*)  (ws + 43*MB + MB/2);
  float* qwf    = (float*)(ws + 43*MB + MB/2 + 256);
  float* kwf    = (float*)(ws + 43*MB + MB/2 + 1280);

  k_detect<<<dim3(1),   dim3(64),  0, stream>>>((const u16*)x_r, flag);
  k_cast  <<<dim3(512), dim3(256), 0, stream>>>(x_r,   xb,   2048*256/4, flag);
  k_cast  <<<dim3(1024),dim3(256), 0, stream>>>(wq_r,  wqb,  4096*256/4, flag);
  k_cast  <<<dim3(128), dim3(256), 0, stream>>>(wkv_r, wkvb, 512*256/4,  flag);
  k_cast  <<<dim3(1024),dim3(256), 0, stream>>>(wo_r,  wob,  256*4096/4, flag);
  k_wprep <<<dim3(1),   dim3(256), 0, stream>>>(qw_r, kw_r, qwf, kwf, flag);
  k_tab   <<<dim3(1024),dim3(256), 0, stream>>>(tab);
  k_qkv     <<<dim3(32, 72),   dim3(256), 0, stream>>>(xb, wqb, wkvb, q_raw, kv_raw);
  k_ropenorm<<<dim3(8704),     dim3(256), 0, stream>>>(q_raw, kv_raw, tab, qwf, kwf, qn, kn);
  k_vtrans  <<<dim3(32, 4),    dim3(256), 0, stream>>>(kv_raw, vt);
  k_attn    <<<dim3(256),      dim3(256), 0, stream>>>(qn, kn, vt, aout);
  k_oproj   <<<dim3(32, 4, 4), dim3(256), 0, stream>>>(aout, wob, pout);
  k_red     <<<dim3(2048),     dim3(256), 0, stream>>>(pout, d_out, flag);
}